// Round 1
// baseline (534.275 us; speedup 1.0000x reference)
//
#include <hip/hip_runtime.h>
#include <hip/hip_bf16.h>
#include <stdint.h>

#define B_N 4
#define S_N 2048
#define DIM_N 1024
#define H_N 16
#define DH_N 64
#define M_ROWS (B_N * S_N)   /* 8192 */
#define BH_N (B_N * H_N)     /* 64 */

typedef unsigned short u16;
typedef __attribute__((ext_vector_type(8))) short short8;
typedef __attribute__((ext_vector_type(4))) float f32x4;

typedef __attribute__((address_space(1))) const void gvoid_t;
typedef __attribute__((address_space(3))) void lvoid_t;

__device__ __forceinline__ u16 f2bf(float f) {
  union { float f; uint32_t u; } c; c.f = f;
  uint32_t u = c.u;
  return (u16)((u + 0x7FFFu + ((u >> 16) & 1u)) >> 16);
}

// ---------------- fp32 -> bf16 conversion (vectorized) ----------------
__global__ void cvt_kernel(const float* __restrict__ src, u16* __restrict__ dst, int n4) {
  int i = blockIdx.x * blockDim.x + threadIdx.x;
  if (i >= n4) return;
  float4 v = reinterpret_cast<const float4*>(src)[i];
  ushort4 o;
  o.x = f2bf(v.x); o.y = f2bf(v.y); o.z = f2bf(v.z); o.w = f2bf(v.w);
  reinterpret_cast<ushort4*>(dst)[i] = o;
}

// ---------------- bf16 GEMM, C[m][n] = sum_k A[m][k]*Bw[n][k] + bias[n] ----
// m97 structure: 128x128 tile, BK=32, 4 waves, global_load_lds width 16.
// MODE 0: bf16 out, permuted [b,h,s,d]   (Q, K)
// MODE 1: bf16 out, transposed [b,h,d,s] (V^T for PV contiguity)
// MODE 2: fp32 out, row-major [m][n]     (final output projection)
template<int MODE>
__global__ __launch_bounds__(256)
void gemm_bt(const u16* __restrict__ A, const u16* __restrict__ Bw,
             const float* __restrict__ bias, void* __restrict__ outp)
{
  __shared__ __align__(16) u16 As[128 * 32];
  __shared__ __align__(16) u16 Bs[128 * 32];
  const int m0 = blockIdx.x * 128, n0 = blockIdx.y * 128;
  const int t = threadIdx.x, w = t >> 6;
  const int l = t & 63, lr = l & 15, lg = l >> 4;
  const int wr = (w >> 1) * 64, wc = (w & 1) * 64;
  const int srow = t >> 2;            // 0..63
  const int skoff = (t & 3) * 8;      // k element offset for 16B chunk

  f32x4 acc[4][4] = {};

  for (int k0 = 0; k0 < DIM_N; k0 += 32) {
    __syncthreads();
#pragma unroll
    for (int c = 0; c < 2; ++c) {
      const u16* ga = A  + (size_t)(m0 + c * 64 + srow) * DIM_N + k0 + skoff;
      const u16* gb = Bw + (size_t)(n0 + c * 64 + srow) * DIM_N + k0 + skoff;
      u16* la = &As[(c * 64 + 16 * w) * 32];   // wave-uniform LDS base
      u16* lb = &Bs[(c * 64 + 16 * w) * 32];
      __builtin_amdgcn_global_load_lds((gvoid_t*)ga, (lvoid_t*)la, 16, 0, 0);
      __builtin_amdgcn_global_load_lds((gvoid_t*)gb, (lvoid_t*)lb, 16, 0, 0);
    }
    __syncthreads();

    short8 af[4], bfr[4];
#pragma unroll
    for (int mf = 0; mf < 4; ++mf)
      af[mf] = *reinterpret_cast<const short8*>(&As[(wr + mf * 16 + lr) * 32 + lg * 8]);
#pragma unroll
    for (int nf = 0; nf < 4; ++nf)
      bfr[nf] = *reinterpret_cast<const short8*>(&Bs[(wc + nf * 16 + lr) * 32 + lg * 8]);
#pragma unroll
    for (int mf = 0; mf < 4; ++mf)
#pragma unroll
      for (int nf = 0; nf < 4; ++nf)
        acc[mf][nf] = __builtin_amdgcn_mfma_f32_16x16x32_bf16(af[mf], bfr[nf], acc[mf][nf], 0, 0, 0);
  }

  float bv[4];
#pragma unroll
  for (int nf = 0; nf < 4; ++nf) bv[nf] = bias[n0 + wc + nf * 16 + lr];

#pragma unroll
  for (int mf = 0; mf < 4; ++mf)
#pragma unroll
    for (int nf = 0; nf < 4; ++nf)
#pragma unroll
      for (int r = 0; r < 4; ++r) {
        int grow = m0 + wr + mf * 16 + lg * 4 + r;   // C row = (lane>>4)*4 + reg
        int gcol = n0 + wc + nf * 16 + lr;           // C col = lane&15
        float v = acc[mf][nf][r] + bv[nf];
        if (MODE == 2) {
          ((float*)outp)[(size_t)grow * DIM_N + gcol] = v;
        } else {
          int b = grow >> 11, s = grow & 2047;
          int h = gcol >> 6, d = gcol & 63;
          size_t idx = (MODE == 0)
            ? ((size_t)(b * H_N + h) * S_N + s) * DH_N + d
            : ((size_t)(b * H_N + h) * DH_N + d) * S_N + s;
          ((u16*)outp)[idx] = f2bf(v);
        }
      }
}

// ---------------- flash attention ----------------
// grid: (S/128, B*H). 4 waves/block, each wave owns 32 q-rows independently.
// K/V read direct from global (512 KB/head -> L2 resident, no staging).
#define LDP 40   // padded P row stride (shorts): 80B, 16B-aligned, conflict-free b128

__global__ __launch_bounds__(256)
void attn_kernel(const u16* __restrict__ Qh, const u16* __restrict__ Kh,
                 const u16* __restrict__ Vt, const uint8_t* __restrict__ mask,
                 u16* __restrict__ AO)
{
  __shared__ __align__(16) u16 P_lds[4][32 * LDP];
  const int w = threadIdx.x >> 6, l = threadIdx.x & 63;
  const int lr = l & 15, lg = l >> 4;
  const int bh = blockIdx.y, b = bh >> 4, h = bh & 15;
  const int qbase = blockIdx.x * 128 + w * 32;

  const u16* Qp = Qh + (size_t)bh * S_N * DH_N;
  const u16* Kp = Kh + (size_t)bh * S_N * DH_N;
  const u16* Vp = Vt + (size_t)bh * DH_N * S_N;
  const uint8_t* mp = mask + (size_t)b * S_N * S_N;

  // Q fragments live in registers all kernel: A-frag row=lane&15, k=8*(lane>>4)+j
  short8 qf[2][2];
#pragma unroll
  for (int mf = 0; mf < 2; ++mf)
#pragma unroll
    for (int ks = 0; ks < 2; ++ks)
      qf[mf][ks] = *reinterpret_cast<const short8*>(
          Qp + (size_t)(qbase + mf * 16 + lr) * DH_N + ks * 32 + lg * 8);

  f32x4 o_acc[2][4] = {};
  float m_s[2][4], l_s[2][4];
#pragma unroll
  for (int mf = 0; mf < 2; ++mf)
#pragma unroll
    for (int r = 0; r < 4; ++r) { m_s[mf][r] = -1e30f; l_s[mf][r] = 0.f; }

  u16* Pw = &P_lds[w][0];

  for (int kc = 0; kc < S_N / 32; ++kc) {
    // --- QK^T on a 32x32 score tile ---
    short8 kf[2][2];
#pragma unroll
    for (int nf = 0; nf < 2; ++nf)
#pragma unroll
      for (int ks = 0; ks < 2; ++ks)
        kf[nf][ks] = *reinterpret_cast<const short8*>(
            Kp + (size_t)(kc * 32 + nf * 16 + lr) * DH_N + ks * 32 + lg * 8);

    f32x4 s_acc[2][2] = {};
#pragma unroll
    for (int ks = 0; ks < 2; ++ks)
#pragma unroll
      for (int mf = 0; mf < 2; ++mf)
#pragma unroll
        for (int nf = 0; nf < 2; ++nf)
          s_acc[mf][nf] = __builtin_amdgcn_mfma_f32_16x16x32_bf16(qf[mf][ks], kf[nf][ks], s_acc[mf][nf], 0, 0, 0);

    // --- scale + mask ---
    float sc[2][2][4];
#pragma unroll
    for (int mf = 0; mf < 2; ++mf)
#pragma unroll
      for (int nf = 0; nf < 2; ++nf)
#pragma unroll
        for (int r = 0; r < 4; ++r) {
          float v = s_acc[mf][nf][r] * 0.125f;
          int row = qbase + mf * 16 + lg * 4 + r;
          int key = kc * 32 + nf * 16 + lr;
          if (mp[(size_t)row * S_N + key]) v = -1e30f;
          sc[mf][nf][r] = v;
        }

    // --- online softmax per row (16-lane wave-parallel reduce) ---
    float alpha[2][4], p[2][2][4];
#pragma unroll
    for (int mf = 0; mf < 2; ++mf)
#pragma unroll
      for (int r = 0; r < 4; ++r) {
        float rx = fmaxf(sc[mf][0][r], sc[mf][1][r]);
        rx = fmaxf(rx, __shfl_xor(rx, 1));
        rx = fmaxf(rx, __shfl_xor(rx, 2));
        rx = fmaxf(rx, __shfl_xor(rx, 4));
        rx = fmaxf(rx, __shfl_xor(rx, 8));
        float mn = fmaxf(m_s[mf][r], rx);
        float al = __expf(m_s[mf][r] - mn);
        float rs = 0.f;
#pragma unroll
        for (int nf = 0; nf < 2; ++nf) {
          float pv = __expf(sc[mf][nf][r] - mn);
          p[mf][nf][r] = pv;
          rs += pv;
        }
        rs += __shfl_xor(rs, 1);
        rs += __shfl_xor(rs, 2);
        rs += __shfl_xor(rs, 4);
        rs += __shfl_xor(rs, 8);
        l_s[mf][r] = l_s[mf][r] * al + rs;
        m_s[mf][r] = mn;
        alpha[mf][r] = al;
      }

    // --- rescale O ---
#pragma unroll
    for (int mf = 0; mf < 2; ++mf)
#pragma unroll
      for (int nf = 0; nf < 4; ++nf)
#pragma unroll
        for (int r = 0; r < 4; ++r)
          o_acc[mf][nf][r] *= alpha[mf][r];

    // --- P (C-layout) -> bf16 -> LDS -> A-fragment layout ---
#pragma unroll
    for (int mf = 0; mf < 2; ++mf)
#pragma unroll
      for (int nf = 0; nf < 2; ++nf)
#pragma unroll
        for (int r = 0; r < 4; ++r)
          Pw[(mf * 16 + lg * 4 + r) * LDP + nf * 16 + lr] = f2bf(p[mf][nf][r]);
    __syncthreads();

    short8 pa[2];
#pragma unroll
    for (int mf = 0; mf < 2; ++mf)
      pa[mf] = *reinterpret_cast<const short8*>(&Pw[(mf * 16 + lr) * LDP + lg * 8]);

    // V B-frags: B[k][d], contiguous along k thanks to V^T layout
    short8 vf[4];
#pragma unroll
    for (int nf = 0; nf < 4; ++nf)
      vf[nf] = *reinterpret_cast<const short8*>(
          Vp + (size_t)(nf * 16 + lr) * S_N + kc * 32 + lg * 8);

#pragma unroll
    for (int mf = 0; mf < 2; ++mf)
#pragma unroll
      for (int nf = 0; nf < 4; ++nf)
        o_acc[mf][nf] = __builtin_amdgcn_mfma_f32_16x16x32_bf16(pa[mf], vf[nf], o_acc[mf][nf], 0, 0, 0);
    __syncthreads();
  }

  // --- finalize: divide by l, store merged [b,s,h*64+d] bf16 ---
#pragma unroll
  for (int mf = 0; mf < 2; ++mf)
#pragma unroll
    for (int nf = 0; nf < 4; ++nf)
#pragma unroll
      for (int r = 0; r < 4; ++r) {
        float v = o_acc[mf][nf][r] / l_s[mf][r];
        int s = qbase + mf * 16 + lg * 4 + r;
        int col = h * DH_N + nf * 16 + lr;
        AO[(size_t)(b * S_N + s) * DIM_N + col] = f2bf(v);
      }
}

// ---------------- launch ----------------
extern "C" void kernel_launch(void* const* d_in, const int* in_sizes, int n_in,
                              void* d_out, int out_size, void* d_ws, size_t ws_size,
                              hipStream_t stream)
{
  const float*   q_in = (const float*)d_in[0];
  const float*   k_in = (const float*)d_in[1];
  const float*   v_in = (const float*)d_in[2];
  const uint8_t* mask = (const uint8_t*)d_in[3];
  const float*   w_q  = (const float*)d_in[4];
  const float*   b_q  = (const float*)d_in[5];
  const float*   w_k  = (const float*)d_in[6];
  const float*   b_k  = (const float*)d_in[7];
  const float*   w_v  = (const float*)d_in[8];
  const float*   b_v  = (const float*)d_in[9];
  const float*   w_o  = (const float*)d_in[10];
  const float*   b_o  = (const float*)d_in[11];

  char* ws = (char*)d_ws;
  size_t off = 0;
  auto alloc = [&](size_t bytes) -> char* {
    char* p = ws + off;
    off += (bytes + 255) & ~(size_t)255;
    return p;
  };
  const size_t act_b = (size_t)M_ROWS * DIM_N * 2;   // 16.8 MB
  const size_t w_b   = (size_t)DIM_N * DIM_N * 2;    // 2 MB
  u16* qb  = (u16*)alloc(act_b);
  u16* kb  = (u16*)alloc(act_b);
  u16* vb  = (u16*)alloc(act_b);
  u16* wqb = (u16*)alloc(w_b);
  u16* wkb = (u16*)alloc(w_b);
  u16* wvb = (u16*)alloc(w_b);
  u16* wob = (u16*)alloc(w_b);
  u16* Qh  = (u16*)alloc(act_b);
  u16* Kh  = (u16*)alloc(act_b);
  u16* Vt  = (u16*)alloc(act_b);
  u16* AO  = qb;   // qb is dead after the Q projection; reuse for merged attn

  const int n4a = M_ROWS * DIM_N / 4;   // 2,097,152
  const int n4w = DIM_N * DIM_N / 4;    // 262,144
  cvt_kernel<<<n4a / 256, 256, 0, stream>>>(q_in, qb, n4a);
  cvt_kernel<<<n4a / 256, 256, 0, stream>>>(k_in, kb, n4a);
  cvt_kernel<<<n4a / 256, 256, 0, stream>>>(v_in, vb, n4a);
  cvt_kernel<<<n4w / 256, 256, 0, stream>>>(w_q, wqb, n4w);
  cvt_kernel<<<n4w / 256, 256, 0, stream>>>(w_k, wkb, n4w);
  cvt_kernel<<<n4w / 256, 256, 0, stream>>>(w_v, wvb, n4w);
  cvt_kernel<<<n4w / 256, 256, 0, stream>>>(w_o, wob, n4w);

  dim3 gg(M_ROWS / 128, DIM_N / 128);
  gemm_bt<0><<<gg, 256, 0, stream>>>(qb, wqb, b_q, Qh);
  gemm_bt<0><<<gg, 256, 0, stream>>>(kb, wkb, b_k, Kh);
  gemm_bt<1><<<gg, 256, 0, stream>>>(vb, wvb, b_v, Vt);

  attn_kernel<<<dim3(S_N / 128, BH_N), 256, 0, stream>>>(Qh, Kh, Vt, mask, AO);

  gemm_bt<2><<<gg, 256, 0, stream>>>(AO, wob, b_o, (float*)d_out);
}

// Round 2
// 410.324 us; speedup vs baseline: 1.3021x; 1.3021x over previous
//
#include <hip/hip_runtime.h>
#include <hip/hip_bf16.h>
#include <stdint.h>

#define B_N 4
#define S_N 2048
#define DIM_N 1024
#define H_N 16
#define DH_N 64
#define M_ROWS (B_N * S_N)   /* 8192 */
#define BH_N (B_N * H_N)     /* 64 */

typedef unsigned short u16;
typedef __attribute__((ext_vector_type(8))) short short8;
typedef __attribute__((ext_vector_type(4))) float f32x4;
typedef __attribute__((ext_vector_type(16))) float f32x16;

typedef __attribute__((address_space(1))) const void gvoid_t;
typedef __attribute__((address_space(3))) void lvoid_t;

__device__ __forceinline__ u16 f2bf(float f) {
  union { float f; uint32_t u; } c; c.f = f;
  uint32_t u = c.u;
  return (u16)((u + 0x7FFFu + ((u >> 16) & 1u)) >> 16);
}

__device__ __forceinline__ uint32_t pk_bf16(float lo, float hi) {
  uint32_t r;
  asm("v_cvt_pk_bf16_f32 %0, %1, %2" : "=v"(r) : "v"(lo), "v"(hi));
  return r;
}

// ---------------- fp32 -> bf16 conversion (vectorized) ----------------
__global__ void cvt_kernel(const float* __restrict__ src, u16* __restrict__ dst, int n4) {
  int i = blockIdx.x * blockDim.x + threadIdx.x;
  if (i >= n4) return;
  float4 v = reinterpret_cast<const float4*>(src)[i];
  ushort4 o;
  o.x = f2bf(v.x); o.y = f2bf(v.y); o.z = f2bf(v.z); o.w = f2bf(v.w);
  reinterpret_cast<ushort4*>(dst)[i] = o;
}

// ---------------- mask -> packed bits (1 bit per bool, 32 keys/word) ------
__global__ void pack_mask(const uint8_t* __restrict__ m, uint32_t* __restrict__ bits, int nwords) {
  int i = blockIdx.x * blockDim.x + threadIdx.x;
  if (i >= nwords) return;
  const uint32_t* p = reinterpret_cast<const uint32_t*>(m) + (size_t)i * 8;
  uint32_t out = 0;
#pragma unroll
  for (int w = 0; w < 8; ++w) {
    uint32_t v = p[w];
    if (v & 0x000000FFu) out |= 1u << (w * 4 + 0);
    if (v & 0x0000FF00u) out |= 1u << (w * 4 + 1);
    if (v & 0x00FF0000u) out |= 1u << (w * 4 + 2);
    if (v & 0xFF000000u) out |= 1u << (w * 4 + 3);
  }
  bits[i] = out;
}

// ---------------- bf16 GEMM, C[m][n] = sum_k A[m][k]*Bw[n][k] + bias[n] ----
// MODE 0: bf16 out, permuted [b,h,s,d]   (Q, K)
// MODE 1: bf16 out, transposed [b,h,d,s] (V^T for PV contiguity)
// MODE 2: fp32 out, row-major [m][n]     (final output projection)
template<int MODE>
__global__ __launch_bounds__(256)
void gemm_bt(const u16* __restrict__ A, const u16* __restrict__ Bw,
             const float* __restrict__ bias, void* __restrict__ outp)
{
  __shared__ __align__(16) u16 As[128 * 32];
  __shared__ __align__(16) u16 Bs[128 * 32];
  const int m0 = blockIdx.x * 128, n0 = blockIdx.y * 128;
  const int t = threadIdx.x, w = t >> 6;
  const int l = t & 63, lr = l & 15, lg = l >> 4;
  const int wr = (w >> 1) * 64, wc = (w & 1) * 64;
  const int srow = t >> 2;
  const int skoff = (t & 3) * 8;

  f32x4 acc[4][4] = {};

  for (int k0 = 0; k0 < DIM_N; k0 += 32) {
    __syncthreads();
#pragma unroll
    for (int c = 0; c < 2; ++c) {
      const u16* ga = A  + (size_t)(m0 + c * 64 + srow) * DIM_N + k0 + skoff;
      const u16* gb = Bw + (size_t)(n0 + c * 64 + srow) * DIM_N + k0 + skoff;
      u16* la = &As[(c * 64 + 16 * w) * 32];
      u16* lb = &Bs[(c * 64 + 16 * w) * 32];
      __builtin_amdgcn_global_load_lds((gvoid_t*)ga, (lvoid_t*)la, 16, 0, 0);
      __builtin_amdgcn_global_load_lds((gvoid_t*)gb, (lvoid_t*)lb, 16, 0, 0);
    }
    __syncthreads();

    short8 af[4], bfr[4];
#pragma unroll
    for (int mf = 0; mf < 4; ++mf)
      af[mf] = *reinterpret_cast<const short8*>(&As[(wr + mf * 16 + lr) * 32 + lg * 8]);
#pragma unroll
    for (int nf = 0; nf < 4; ++nf)
      bfr[nf] = *reinterpret_cast<const short8*>(&Bs[(wc + nf * 16 + lr) * 32 + lg * 8]);
#pragma unroll
    for (int mf = 0; mf < 4; ++mf)
#pragma unroll
      for (int nf = 0; nf < 4; ++nf)
        acc[mf][nf] = __builtin_amdgcn_mfma_f32_16x16x32_bf16(af[mf], bfr[nf], acc[mf][nf], 0, 0, 0);
  }

  float bv[4];
#pragma unroll
  for (int nf = 0; nf < 4; ++nf) bv[nf] = bias[n0 + wc + nf * 16 + lr];

#pragma unroll
  for (int mf = 0; mf < 4; ++mf)
#pragma unroll
    for (int nf = 0; nf < 4; ++nf)
#pragma unroll
      for (int r = 0; r < 4; ++r) {
        int grow = m0 + wr + mf * 16 + lg * 4 + r;
        int gcol = n0 + wc + nf * 16 + lr;
        float v = acc[mf][nf][r] + bv[nf];
        if (MODE == 2) {
          ((float*)outp)[(size_t)grow * DIM_N + gcol] = v;
        } else {
          int b = grow >> 11, s = grow & 2047;
          int h = gcol >> 6, d = gcol & 63;
          size_t idx = (MODE == 0)
            ? ((size_t)(b * H_N + h) * S_N + s) * DH_N + d
            : ((size_t)(b * H_N + h) * DH_N + d) * S_N + s;
          ((u16*)outp)[idx] = f2bf(v);
        }
      }
}

// ---------------- flash attention, swapped-operand 32x32 structure --------
// grid: (S/128, B*H). 4 independent waves/block, each owns 32 q-rows.
// No LDS, no barriers. Lane l owns q-row q0+(l&31) for scores AND O^T cols.
#define AT_WAVES 4

__global__ __launch_bounds__(256)
void attn_kernel(const u16* __restrict__ Qh, const u16* __restrict__ Kh,
                 const u16* __restrict__ Vt, const uint32_t* __restrict__ mbits,
                 u16* __restrict__ AO)
{
  const int w = threadIdx.x >> 6, l = threadIdx.x & 63;
  const int l31 = l & 31, hl = l >> 5;
  const int bh = blockIdx.y, b = bh >> 4, h = bh & 15;
  const int q = blockIdx.x * (AT_WAVES * 32) + w * 32 + l31;

  const u16* Qp = Qh + (size_t)bh * S_N * DH_N;
  const u16* Kp = Kh + (size_t)bh * S_N * DH_N;
  const u16* Vp = Vt + (size_t)bh * DH_N * S_N;
  const uint32_t* mrow = mbits + ((size_t)b * S_N + q) * (S_N / 32);

  // Q as B-operand (col = l&31 = q, k-dim d = 16u + 8*hl + j), lives all kernel
  short8 qf[4];
#pragma unroll
  for (int u = 0; u < 4; ++u)
    qf[u] = *reinterpret_cast<const short8*>(Qp + (size_t)q * DH_N + u * 16 + hl * 8);

  f32x16 oacc[2] = {};
  float m_run = -1e30f, l_run = 0.f;
  const float c1 = 0.18033688011112042f;   // 0.125 * log2(e)

  for (int kc = 0; kc < S_N / 32; ++kc) {
    // --- K as A-operand (row = l&31 = key, k-dim d), 4 frags over d=64 ---
    const u16* kbase = Kp + (size_t)(kc * 32 + l31) * DH_N + hl * 8;
    short8 kf0 = *reinterpret_cast<const short8*>(kbase);
    short8 kf1 = *reinterpret_cast<const short8*>(kbase + 16);
    short8 kf2 = *reinterpret_cast<const short8*>(kbase + 32);
    short8 kf3 = *reinterpret_cast<const short8*>(kbase + 48);

    f32x16 sacc = {};
    sacc = __builtin_amdgcn_mfma_f32_32x32x16_bf16(kf0, qf[0], sacc, 0, 0, 0);
    sacc = __builtin_amdgcn_mfma_f32_32x32x16_bf16(kf1, qf[1], sacc, 0, 0, 0);
    sacc = __builtin_amdgcn_mfma_f32_32x32x16_bf16(kf2, qf[2], sacc, 0, 0, 0);
    sacc = __builtin_amdgcn_mfma_f32_32x32x16_bf16(kf3, qf[3], sacc, 0, 0, 0);

    // --- issue V loads early (A-operand for O^T: row = d = 32nf+l31, k = key) ---
    short8 vf[2][2];
#pragma unroll
    for (int ks = 0; ks < 2; ++ks)
#pragma unroll
      for (int nf = 0; nf < 2; ++nf)
        vf[ks][nf] = *reinterpret_cast<const short8*>(
            Vp + (size_t)(nf * 32 + l31) * S_N + kc * 32 + ks * 16 + hl * 8);

    // --- softmax in exp2 domain; lane-local row (key r -> (r&3)+8*(r>>2)+4*hl) ---
    float t[16];
#pragma unroll
    for (int r = 0; r < 16; ++r) t[r] = sacc[r] * c1;

    uint32_t mw = mrow[kc];
    if (mw) {
#pragma unroll
      for (int r = 0; r < 16; ++r)
        if ((mw >> ((r & 3) + 8 * (r >> 2) + 4 * hl)) & 1) t[r] = -1e30f;
    }

    float mx = t[0];
#pragma unroll
    for (int r = 1; r < 16; ++r) mx = fmaxf(mx, t[r]);
    mx = fmaxf(mx, __shfl_xor(mx, 32));
    float mnew = fmaxf(m_run, mx);
    float alpha = __builtin_amdgcn_exp2f(m_run - mnew);

    float p[16];
    float rs = 0.f;
#pragma unroll
    for (int r = 0; r < 16; ++r) {
      p[r] = __builtin_amdgcn_exp2f(t[r] - mnew);
      rs += p[r];
    }
    rs += __shfl_xor(rs, 32);
    l_run = l_run * alpha + rs;
    m_run = mnew;

    oacc[0] *= alpha;
    oacc[1] *= alpha;

    // --- P -> bf16 B-operand frags via cvt_pk + cross-half swap (T12) ---
    // lane holds keys {(r&3)+8*(r>>2)+4*hl}; B-frag needs keys 16*ks+8*hl+j.
    uint32_t A0 = pk_bf16(p[0], p[1]),  A1 = pk_bf16(p[2], p[3]);
    uint32_t B0 = pk_bf16(p[4], p[5]),  B1 = pk_bf16(p[6], p[7]);
    uint32_t s1 = __shfl_xor(hl ? A0 : B0, 32);
    uint32_t s2 = __shfl_xor(hl ? A1 : B1, 32);
    union { uint32_t u[4]; short8 s8; } pf0, pf1;
    pf0.u[0] = hl ? s1 : A0;  pf0.u[1] = hl ? s2 : A1;
    pf0.u[2] = hl ? B0 : s1;  pf0.u[3] = hl ? B1 : s2;

    uint32_t C0 = pk_bf16(p[8], p[9]),   C1 = pk_bf16(p[10], p[11]);
    uint32_t D0 = pk_bf16(p[12], p[13]), D1 = pk_bf16(p[14], p[15]);
    uint32_t s3 = __shfl_xor(hl ? C0 : D0, 32);
    uint32_t s4 = __shfl_xor(hl ? C1 : D1, 32);
    pf1.u[0] = hl ? s3 : C0;  pf1.u[1] = hl ? s4 : C1;
    pf1.u[2] = hl ? D0 : s3;  pf1.u[3] = hl ? D1 : s4;

    // --- O^T += V^T . P : lane keeps col q = l&31, rows d ---
    oacc[0] = __builtin_amdgcn_mfma_f32_32x32x16_bf16(vf[0][0], pf0.s8, oacc[0], 0, 0, 0);
    oacc[0] = __builtin_amdgcn_mfma_f32_32x32x16_bf16(vf[1][0], pf1.s8, oacc[0], 0, 0, 0);
    oacc[1] = __builtin_amdgcn_mfma_f32_32x32x16_bf16(vf[0][1], pf0.s8, oacc[1], 0, 0, 0);
    oacc[1] = __builtin_amdgcn_mfma_f32_32x32x16_bf16(vf[1][1], pf1.s8, oacc[1], 0, 0, 0);
  }

  // --- finalize: O^T[d][q]/l -> AO[b, q, h*64+d] (8B packed stores) ---
  float inv_l = 1.0f / l_run;
  u16* orow = AO + ((size_t)b * S_N + q) * DIM_N + h * DH_N;
#pragma unroll
  for (int nf = 0; nf < 2; ++nf)
#pragma unroll
    for (int g = 0; g < 4; ++g) {
      ushort4 v4;
      v4.x = f2bf(oacc[nf][g * 4 + 0] * inv_l);
      v4.y = f2bf(oacc[nf][g * 4 + 1] * inv_l);
      v4.z = f2bf(oacc[nf][g * 4 + 2] * inv_l);
      v4.w = f2bf(oacc[nf][g * 4 + 3] * inv_l);
      *reinterpret_cast<ushort4*>(orow + nf * 32 + g * 8 + hl * 4) = v4;
    }
}

// ---------------- launch ----------------
extern "C" void kernel_launch(void* const* d_in, const int* in_sizes, int n_in,
                              void* d_out, int out_size, void* d_ws, size_t ws_size,
                              hipStream_t stream)
{
  const float*   q_in = (const float*)d_in[0];
  const float*   k_in = (const float*)d_in[1];
  const float*   v_in = (const float*)d_in[2];
  const uint8_t* mask = (const uint8_t*)d_in[3];
  const float*   w_q  = (const float*)d_in[4];
  const float*   b_q  = (const float*)d_in[5];
  const float*   w_k  = (const float*)d_in[6];
  const float*   b_k  = (const float*)d_in[7];
  const float*   w_v  = (const float*)d_in[8];
  const float*   b_v  = (const float*)d_in[9];
  const float*   w_o  = (const float*)d_in[10];
  const float*   b_o  = (const float*)d_in[11];

  char* ws = (char*)d_ws;
  size_t off = 0;
  auto alloc = [&](size_t bytes) -> char* {
    char* p = ws + off;
    off += (bytes + 255) & ~(size_t)255;
    return p;
  };
  const size_t act_b = (size_t)M_ROWS * DIM_N * 2;
  const size_t w_b   = (size_t)DIM_N * DIM_N * 2;
  const int    nmw   = B_N * S_N * (S_N / 32);       // 524288 mask words
  u16* qb  = (u16*)alloc(act_b);
  u16* kb  = (u16*)alloc(act_b);
  u16* vb  = (u16*)alloc(act_b);
  u16* wqb = (u16*)alloc(w_b);
  u16* wkb = (u16*)alloc(w_b);
  u16* wvb = (u16*)alloc(w_b);
  u16* wob = (u16*)alloc(w_b);
  u16* Qh  = (u16*)alloc(act_b);
  u16* Kh  = (u16*)alloc(act_b);
  u16* Vt  = (u16*)alloc(act_b);
  uint32_t* mbits = (uint32_t*)alloc((size_t)nmw * 4);
  u16* AO  = qb;   // qb dead after Q projection; reuse for merged attn out

  const int n4a = M_ROWS * DIM_N / 4;
  const int n4w = DIM_N * DIM_N / 4;
  cvt_kernel<<<n4a / 256, 256, 0, stream>>>(q_in, qb, n4a);
  cvt_kernel<<<n4a / 256, 256, 0, stream>>>(k_in, kb, n4a);
  cvt_kernel<<<n4a / 256, 256, 0, stream>>>(v_in, vb, n4a);
  cvt_kernel<<<n4w / 256, 256, 0, stream>>>(w_q, wqb, n4w);
  cvt_kernel<<<n4w / 256, 256, 0, stream>>>(w_k, wkb, n4w);
  cvt_kernel<<<n4w / 256, 256, 0, stream>>>(w_v, wvb, n4w);
  cvt_kernel<<<n4w / 256, 256, 0, stream>>>(w_o, wob, n4w);
  pack_mask<<<nmw / 256, 256, 0, stream>>>(mask, mbits, nmw);

  dim3 gg(M_ROWS / 128, DIM_N / 128);
  gemm_bt<0><<<gg, 256, 0, stream>>>(qb, wqb, b_q, Qh);
  gemm_bt<0><<<gg, 256, 0, stream>>>(kb, wkb, b_k, Kh);
  gemm_bt<1><<<gg, 256, 0, stream>>>(vb, wvb, b_v, Vt);

  attn_kernel<<<dim3(S_N / (AT_WAVES * 32), BH_N), 256, 0, stream>>>(Qh, Kh, Vt, mbits, AO);

  gemm_bt<2><<<gg, 256, 0, stream>>>(AO, wob, b_o, (float*)d_out);
}